// Round 10
// baseline (51.349 us; speedup 1.0000x reference)
//
#include <hip/hip_runtime.h>
#include <stdint.h>

// MBSeederSLFCAMS — exact JAX replication; fused kernel, hidden background emit.
#define PARTITIONABLE 1

typedef unsigned int u32;
typedef unsigned long long u64;
typedef __attribute__((ext_vector_type(4))) int int4v;

static constexpr int BB  = 256;
static constexpr int HWN = 65536;
static constexpr u32 K_BG = 6553;
static constexpr u32 TOPK = 100;
static constexpr u32 CAP  = 7936;
static constexpr u32 FG_CAP = 1024;

// ---- arena (bytes); live ranges audited per barrier interval
static constexpr int OFF_LST   = 0;        // u64[7936]  62KB  ph1..bg-mark
static constexpr int OFF_FVL   = 0;        // u64[1024]  dilate (lst dead)
static constexpr int OFF_BVL   = 8192;
static constexpr int OFF_FHL   = 16384;
static constexpr int OFF_BHL   = 24576;
static constexpr int OFF_CIMG  = 63488;    // u32[16384] 64KB  ph1..ROI
static constexpr int OFF_FGL   = 63488;    // u64[1024]  fg list (cImg dead)
static constexpr int OFF_SEEDB = 71680;    // u64[1024]
static constexpr int OFF_SEEDF = 79872;    // u64[1024]
static constexpr int OFF_HIST  = 129024;   // u32[4096]  16KB
static constexpr int OFF_HROWS = 137216;   // u64[1024]
static constexpr int OFF_ROWS  = 145408;   // u64[1024]
static constexpr int OFF_HO    = 153600;   // u32[256]
static constexpr int OFF_EQ    = 154624;   // u32[256]
static constexpr int OFF_SCAL  = 155648;   // u32[32]
static constexpr int ARENA_BYTES = 155776; // < 160 KiB

__host__ __device__ inline u32 rotl32(u32 x, int d) { return (x << d) | (x >> (32 - d)); }

#define TF_ROUND(r) do { x0 += x1; x1 = rotl32(x1, r); x1 ^= x0; } while (0)

__host__ __device__ inline void threefry2x32(u32 k0, u32 k1, u32 x0, u32 x1, u32& o0, u32& o1) {
  u32 ks2 = k0 ^ k1 ^ 0x1BD11BDAu;
  x0 += k0; x1 += k1;
  TF_ROUND(13); TF_ROUND(15); TF_ROUND(26); TF_ROUND(6);
  x0 += k1;  x1 += ks2 + 1u;
  TF_ROUND(17); TF_ROUND(29); TF_ROUND(16); TF_ROUND(24);
  x0 += ks2; x1 += k0 + 2u;
  TF_ROUND(13); TF_ROUND(15); TF_ROUND(26); TF_ROUND(6);
  x0 += k0;  x1 += k1 + 3u;
  TF_ROUND(17); TF_ROUND(29); TF_ROUND(16); TF_ROUND(24);
  x0 += k1;  x1 += ks2 + 4u;
  TF_ROUND(13); TF_ROUND(15); TF_ROUND(26); TF_ROUND(6);
  x0 += ks2; x1 += k0 + 5u;
  o0 = x0; o1 = x1;
}

__device__ inline u32 score_bits(u32 k0, u32 k1, u32 i) {
#if PARTITIONABLE
  u32 a, b;
  threefry2x32(k0, k1, 0u, i, a, b);
  return a ^ b;
#else
  const u32 HALF = 1u << 23;
  u32 a, b;
  if (i < HALF) { threefry2x32(k0, k1, i, i + HALF, a, b); return a; }
  threefry2x32(k0, k1, i - HALF, i, a, b); return b;
#endif
}

__device__ __forceinline__ u32 wscan_incl(u32 v, int lane) {
#pragma unroll
  for (int d = 1; d < 64; d <<= 1) { u32 t = __shfl_up(v, d, 64); if (lane >= d) v += t; }
  return v;
}

// ---- parallel rank-select split in two halves around a barrier.
template<int BPT, int NT>
__device__ __forceinline__ void pselA(const u32* hist, u32* ws, int t, u32* h, u32& loc, u32& inc) {
  int lane = t & 63;
  loc = 0;
#pragma unroll
  for (int j = 0; j < BPT; j++) { h[j] = hist[BPT * t + j]; loc += h[j]; }
  inc = wscan_incl(loc, lane);
  if (lane == 63) ws[t >> 6] = inc;
}
template<int BPT, int NT>
__device__ __forceinline__ void pselB(u32 K, bool desc, const u32* ws, u32* sc, int t, const u32* h, u32 loc, u32 inc) {
  const int NW = NT / 64;
  int wid = t >> 6;
  u32 off = 0, total = 0;
#pragma unroll
  for (int k = 0; k < NW; k++) { u32 wv = ws[k]; total += wv; if (k < wid) off += wv; }
  inc += off;
  if (!desc) {
    u32 ex = inc - loc;
#pragma unroll
    for (int j = 0; j < BPT; j++) { if (ex < K && K <= ex + h[j]) { sc[0] = BPT * t + j; sc[1] = K - ex; } ex += h[j]; }
  } else {
    u32 ex = total - inc;
#pragma unroll
    for (int j = BPT - 1; j >= 0; j--) { if (ex < K && K <= ex + h[j]) { sc[0] = BPT * t + j; sc[1] = K - ex; } ex += h[j]; }
  }
}

// ---- full psel with internal barriers (cold paths); zeroes hist[0..zeroN)
template<int BPT, int NT>
__device__ void psel_full(u32* hist, u32 K, bool desc, u32* ws, u32* sc, int zeroN, int tid) {
  u32 h[BPT], loc = 0, inc = 0;
  bool act = tid < NT;
  if (act) pselA<BPT, NT>(hist, ws, tid, h, loc, inc);
  __syncthreads();
  if (act) pselB<BPT, NT>(K, desc, ws, sc, tid, h, loc, inc);
  for (int k = tid; k < zeroN; k += 1024) hist[k] = 0;
  __syncthreads();
}

// ---- register-only Otsu on wave 0 (no barriers). Writes scal[8]=thi, scal[5]=bad.
__device__ __forceinline__ void otsu_wave0(const u32* hO, u32* scal, int lane) {
  u32 base = (u32)lane * 4;
  u32 h[4], cw[4], cs[4];
#pragma unroll
  for (int j = 0; j < 4; j++) h[j] = hO[base + j];
  cw[0] = h[0]; cs[0] = h[0] * base;
#pragma unroll
  for (int j = 1; j < 4; j++) { cw[j] = cw[j-1] + h[j]; cs[j] = cs[j-1] + h[j] * (base + j); }
  u32 incW = wscan_incl(cw[3], lane);
  u32 incS = wscan_incl(cs[3], lane);
  u32 offW = incW - cw[3], offS = incS - cs[3];
  u32 totW = __shfl(incW, 63, 64), totS = __shfl(incS, 63, 64);
  int nz = 0;
#pragma unroll
  for (int j = 0; j < 4; j++) nz += (h[j] != 0);
#pragma unroll
  for (int d = 1; d < 64; d <<= 1) nz += __shfl_xor(nz, d, 64);
  u32 selfW0 = cw[0] + offW, selfS0 = cs[0] + offS;
  u32 nxtW = __shfl_down(selfW0, 1, 64);
  u32 nxtS = __shfl_down(selfS0, 1, 64);
  u32 nxtH = __shfl_down(h[0], 1, 64);
  float total = (float)totW, stot = (float)totS;
  unsigned long long best = 0ull;
#pragma unroll
  for (int j = 0; j < 4; j++) {
    int t = (int)base + j;
    if (t < 255) {
      float h1 = (float)((j < 3) ? h[j+1] : nxtH);
      float w1 = (float)(cw[j] + offW);
      float w1n = (j < 3) ? (float)(cw[j+1] + offW) : (float)nxtW;
      float s1 = (float)(cs[j] + offS);
      float s1n = (j < 3) ? (float)(cs[j+1] + offS) : (float)nxtS;
      float w2 = total - w1n + h1;
      float s2 = stot - s1n + h1 * (float)(t + 1);
      float m1 = s1 / fmaxf(w1, 1.0f);
      float m2 = s2 / fmaxf(w2, 1.0f);
      float d = m1 - m2;
      float v = (w1 * w2) * (d * d);
      unsigned long long key = ((unsigned long long)__float_as_uint(v) << 32) | (u32)(255 - t);
      if (key > best) best = key;
    }
  }
#pragma unroll
  for (int d = 1; d < 64; d <<= 1) { unsigned long long o = __shfl_xor(best, d, 64); if (o > best) best = o; }
  if (lane == 0) {
    int bi = 255 - (int)(best & 0xFFFFFFFFu);
    float th = (float)bi;
    th = (th <= 0.0f) ? 1.0f : ((th >= 255.0f) ? 254.0f : th);
    scal[8] = (u32)(int)th;
    scal[5] = (nz <= 1) ? 1u : 0u;
  }
}

__device__ __forceinline__ void roi_bits(const u32* cImgW, u64* rows, u32 thiU, int tid) {
  u64 bits = 0;
#pragma unroll
  for (int k2 = 0; k2 < 16; k2++) {
    int k = (k2 + (tid >> 1)) & 15;
    u32 v4 = cImgW[tid * 16 + k];
    u32 m = 0;
    if ((v4 & 0xFFu) > thiU)         m |= 1u;
    if (((v4 >> 8) & 0xFFu) > thiU)  m |= 2u;
    if (((v4 >> 16) & 0xFFu) > thiU) m |= 4u;
    if ((v4 >> 24) > thiU)           m |= 8u;
    bits |= (u64)m << (4 * k);
  }
  rows[tid] = bits;
}

__device__ __forceinline__ void erode_h(const u64* rows, u64* hrows, int r) {
  u64 wv[4], h0[4];
  for (int j = 0; j < 4; j++) { wv[j] = rows[r * 4 + j]; h0[j] = wv[j]; }
  for (int s = 1; s <= 5; s++)
    for (int j = 0; j < 4; j++) {
      u64 hi = (j < 3) ? wv[j + 1] : ~0ull;
      u64 lo = (j > 0) ? wv[j - 1] : ~0ull;
      h0[j] &= ((wv[j] >> s) | (hi << (64 - s))) & ((wv[j] << s) | (lo >> (64 - s)));
    }
  for (int j = 0; j < 4; j++) hrows[r * 4 + j] = h0[j];
}

__device__ __forceinline__ void erode_v(const u64* hrows, u64* rows, int r) {
  u64 res[4] = {hrows[r * 4], hrows[r * 4 + 1], hrows[r * 4 + 2], hrows[r * 4 + 3]};
  for (int dr = -5; dr <= 5; dr++) {
    if (dr == 0) continue;
    int rr = r + dr;
    if (rr < 0 || rr >= 256) continue;
    for (int j = 0; j < 4; j++) res[j] &= hrows[rr * 4 + j];
  }
  for (int j = 0; j < 4; j++) rows[r * 4 + j] = res[j];
}

// ---- generic top-100 seeding from an idx list (cold fg path).
__device__ void seed_generic(u64* lst2, u32 n, u32 k0, u32 k1, u32 bimg, u64* seedRows,
                             u32* hist, u32* eqA, u32* scal, u32* ws, bool dead, int tid) {
  u32* sc = scal + 2;
  seedRows[tid] = 0;
  for (u32 e = tid; e < n; e += 1024) {
    u32 idx = (u32)(lst2[e] & 0xFFFFu);
    u32 m = score_bits(k0, k1, (bimg << 16) | idx) >> 9;
    lst2[e] = ((u64)m << 16) | idx;
    atomicAdd(&hist[m >> 12], 1u);
  }
  if (tid == 0) scal[1] = 0;
  __syncthreads();
  u32 keff = n < TOPK ? n : TOPK;
  psel_full<2, 1024>(hist, keff, true, ws, sc, 4096, tid);
  u32 s0 = sc[0], Kr = sc[1];
  for (u32 e = tid; e < n; e += 1024) { u32 m = (u32)(lst2[e] >> 16); if ((m >> 12) == s0) atomicAdd(&hist[m & 0xFFFu], 1u); }
  __syncthreads();
  psel_full<4, 1024>(hist, Kr, true, ws, sc, 4096, tid);
  u32 S = (s0 << 12) | sc[0]; u32 tiesS = sc[1];
  for (u32 e = tid; e < n; e += 1024) {
    u64 le = lst2[e]; u32 m = (u32)(le >> 16); u32 idx = (u32)(le & 0xFFFFu);
    if (m > S) { if (!dead) atomicOr(&seedRows[idx >> 6], 1ull << (idx & 63)); }
    else if (m == S) { u32 p = atomicAdd(&scal[1], 1u); if (p < 256) eqA[p] = idx; }
  }
  __syncthreads();
  if (tid == 0) {
    u32 ne = scal[1] < 256u ? scal[1] : 256u;
    for (u32 i2 = 1; i2 < ne; i2++) { u32 v = eqA[i2]; int j = (int)i2 - 1; while (j >= 0 && eqA[j] > v) { eqA[j + 1] = eqA[j]; j--; } eqA[j + 1] = v; }
    scal[4] = ne;
  }
  __syncthreads();
  { u32 ne = scal[4]; u32 tk = tiesS < ne ? tiesS : ne;
    if (!dead && (u32)tid < tk) { u32 idx = eqA[tid]; atomicOr(&seedRows[idx >> 6], 1ull << (idx & 63)); } }
  __syncthreads();
}

__global__ __launch_bounds__(1024, 4) void k_all(const float* __restrict__ x,
                                                 u32 kf0, u32 kf1, u32 kb0, u32 kb1,
                                                 int* __restrict__ out) {
  __shared__ __align__(16) char arena[ARENA_BYTES];
  const int b = blockIdx.x, tid = threadIdx.x;
  const int lane = tid & 63;

  u64* lst    = (u64*)(arena + OFF_LST);
  u32* cImgW  = (u32*)(arena + OFF_CIMG);
  u32* hO     = (u32*)(arena + OFF_HO);
  u32* hist   = (u32*)(arena + OFF_HIST);
  u32* eqA    = (u32*)(arena + OFF_EQ);
  u32* scal   = (u32*)(arena + OFF_SCAL);
  u32* ws     = scal + 10;
  u32* sc     = scal + 2;
  u64* rows   = (u64*)(arena + OFF_ROWS);
  u64* hrows  = (u64*)(arena + OFF_HROWS);
  u64* fgList = (u64*)(arena + OFF_FGL);
  u64* seedB  = (u64*)(arena + OFF_SEEDB);
  u64* seedF  = (u64*)(arena + OFF_SEEDF);

  const u32 BND = __float_as_uint(0.110f);
  const float4* img4 = (const float4*)(x + (size_t)b * HWN);
  const float* img = x + (size_t)b * HWN;
  int4v* out4 = (int4v*)(out + (size_t)b * HWN);

  // ---- I0: zero
  if (tid < 256) hO[tid] = 0;
  hist[tid] = 0; hist[tid + 1024] = 0;
  if (tid < 10) scal[tid] = 0;
  __syncthreads();

  // ---- I1: single scan: cImg pack, otsu hist, cam-stage1 count, scan-based push
#pragma unroll
  for (int half = 0; half < 2; ++half) {
    float4 v[8];
#pragma unroll
    for (int k = 0; k < 8; k++) v[k] = img4[((half * 8 + k) << 10) + tid];
    u32 nq = 0;
#pragma unroll
    for (int k = 0; k < 8; k++) {
      u32 c0 = (u32)(int)(v[k].x * 255.0f);
      u32 c1 = (u32)(int)(v[k].y * 255.0f);
      u32 c2 = (u32)(int)(v[k].z * 255.0f);
      u32 c3 = (u32)(int)(v[k].w * 255.0f);
      atomicAdd(&hO[c0], 1u); atomicAdd(&hO[c1], 1u);
      atomicAdd(&hO[c2], 1u); atomicAdd(&hO[c3], 1u);
      cImgW[((half * 8 + k) << 10) + tid] = c0 | (c1 << 8) | (c2 << 16) | (c3 << 24);
      u32 q0 = __float_as_uint(v[k].x), q1 = __float_as_uint(v[k].y);
      u32 q2 = __float_as_uint(v[k].z), q3 = __float_as_uint(v[k].w);
      if (q0 < BND) { nq++; atomicAdd(&hist[q0 >> 19], 1u); }
      if (q1 < BND) { nq++; atomicAdd(&hist[q1 >> 19], 1u); }
      if (q2 < BND) { nq++; atomicAdd(&hist[q2 >> 19], 1u); }
      if (q3 < BND) { nq++; atomicAdd(&hist[q3 >> 19], 1u); }
    }
    u32 incl = wscan_incl(nq, lane);
    u32 wtot = __shfl(incl, 63, 64);
    u32 base = 0;
    if (lane == 0) base = atomicAdd(&scal[0], wtot);
    base = __shfl(base, 0, 64);
    u32 pos = base + incl - nq;
#pragma unroll
    for (int k = 0; k < 8; k++) {
      u32 q0 = __float_as_uint(v[k].x), q1 = __float_as_uint(v[k].y);
      u32 q2 = __float_as_uint(v[k].z), q3 = __float_as_uint(v[k].w);
      u32 pix = (u32)((((half * 8 + k) << 10) + tid) * 4);
      if (q0 < BND) { if (pos < CAP) lst[pos] = ((u64)q0 << 16) | pix; pos++; }
      if (q1 < BND) { if (pos < CAP) lst[pos] = ((u64)q1 << 16) | (pix + 1); pos++; }
      if (q2 < BND) { if (pos < CAP) lst[pos] = ((u64)q2 << 16) | (pix + 2); pos++; }
      if (q3 < BND) { if (pos < CAP) lst[pos] = ((u64)q3 << 16) | (pix + 3); pos++; }
    }
  }
  __syncthreads();
  u32 cntBelow = scal[0];
  bool fastOK = (cntBelow >= K_BG && cntBelow <= CAP);

  // ---- background fill: entire image = -255 via nt stores. No consumers —
  // drains through the write pipe in parallel with the LDS-bound select
  // ladder below. The final sparse emit (after many barriers, hence ordered)
  // only rewrites int4 groups near seeds.
  {
    int4v neg; neg.x = -255; neg.y = -255; neg.z = -255; neg.w = -255;
#pragma unroll
    for (int it = 0; it < 16; it++)
      __builtin_nontemporal_store(neg, out4 + it * 1024 + tid);
  }

  // ---- I2a: Otsu (wave 0) ∥ cam psel stage1 scan (tid>=512)
  {
    u32 h1v[4], loc1 = 0, inc1 = 0;
    if (tid < 64) otsu_wave0(hO, scal, lane);
    if (tid >= 512) pselA<4, 512>(hist, ws, tid - 512, h1v, loc1, inc1);
    __syncthreads();
    // ---- I2b: psel stage1 finish ∥ zero hist[0..2047] (tid<512)
    if (tid >= 512) pselB<4, 512>(K_BG, false, ws, sc, tid - 512, h1v, loc1, inc1);
    else { hist[tid*4] = 0; hist[tid*4+1] = 0; hist[tid*4+2] = 0; hist[tid*4+3] = 0; }
    __syncthreads();
  }
  u32 thiU = scal[8];
  bool dead = scal[5] != 0u;

  u32 listN;
  if (fastOK) {
    listN = cntBelow;
    u32 cb0 = sc[0], Kb = sc[1];
    // ---- I4: stage2 count ∥ ROI bits
    for (u32 e = tid; e < listN; e += 1024) { u32 q = (u32)(lst[e] >> 16); if ((q >> 19) == cb0) atomicAdd(&hist[(q >> 8) & 0x7FFu], 1u); }
    roi_bits(cImgW, rows, thiU, tid);
    __syncthreads();
    // ---- I5a: psel stage2 scan (tid<512) ∥ erosion-h (512..767)
    u32 h2v[4], loc2 = 0, inc2 = 0;
    if (tid < 512) pselA<4, 512>(hist, ws, tid, h2v, loc2, inc2);
    else if (tid < 768) erode_h(rows, hrows, tid - 512);
    __syncthreads();
    // ---- I5b: psel stage2 finish ∥ erosion-v (512..767)
    if (tid < 512) pselB<4, 512>(Kb, false, ws, sc, tid, h2v, loc2, inc2);
    else if (tid < 768) erode_v(hrows, rows, tid - 512);
    __syncthreads();
    u32 cb1 = sc[0], Kc = sc[1];
    u32 hi22 = (cb0 << 11) | cb1;
    // ---- I6: collect stage3-bin entries ∥ fg extract ∥ zero hist[0..4095]
    for (u32 e = tid; e < listN; e += 1024) {
      u64 le = lst[e]; u32 q = (u32)(le >> 16);
      if ((q >> 8) == hi22) { u32 p = atomicAdd(&scal[1], 1u); if (p < 256) eqA[p] = ((q & 0xFFu) << 16) | (u32)(le & 0xFFFFu); }
    }
    { u64 wv = rows[tid];
      while (wv) { int bit = __ffsll((long long)wv) - 1; wv &= wv - 1; u32 p = atomicAdd(&scal[7], 1u); if (p < FG_CAP) fgList[p] = (u64)(u32)(tid * 64 + bit); } }
    hist[tid] = 0; hist[tid + 1024] = 0; hist[tid + 2048] = 0; hist[tid + 3072] = 0;
    __syncthreads();
    // ---- I7: exact finish — sort bin entries asc by (low8, idx); rank-Kc element
    if (tid == 0) {
      u32 ne = scal[1] < 256u ? scal[1] : 256u;
      for (u32 i2 = 1; i2 < ne; i2++) { u32 v = eqA[i2]; int j = (int)i2 - 1; while (j >= 0 && eqA[j] > v) { eqA[j + 1] = eqA[j]; j--; } eqA[j + 1] = v; }
      u32 ent = eqA[Kc - 1];
      scal[26] = (hi22 << 8) | (ent >> 16);   // T (full float bits)
      scal[27] = ent & 0xFFFFu;               // tie-max idx at T
    }
    __syncthreads();
  } else {
    // ======== cold exact fallback: full-range recount from global ========
    for (int k2 = tid; k2 < 4096; k2 += 1024) hist[k2] = 0;
    __syncthreads();
    for (int c = 0; c < 64; c++) atomicAdd(&hist[__float_as_uint(img[(c << 10) + tid]) >> 19], 1u);
    __syncthreads();
    psel_full<2, 1024>(hist, K_BG, false, ws, sc, 2048, tid);
    u32 cb0 = sc[0], Kb = sc[1];
    if (tid == 0) scal[0] = 0;
    __syncthreads();
    for (int c = 0; c < 64; c++) {
      int i = (c << 10) + tid; u32 q = __float_as_uint(img[i]);
      if ((q >> 19) == cb0) { u32 p = atomicAdd(&scal[0], 1u); if (p < CAP) lst[p] = ((u64)q << 16) | (u32)i; }
    }
    __syncthreads();
    u32 ln = scal[0] < CAP ? scal[0] : CAP;
    for (u32 e = tid; e < ln; e += 1024) { u32 q = (u32)(lst[e] >> 16); atomicAdd(&hist[(q >> 8) & 0x7FFu], 1u); }
    __syncthreads();
    psel_full<2, 1024>(hist, Kb, false, ws, sc, 256, tid);
    u32 cb1 = sc[0], Kc = sc[1];
    u32 hi22 = (cb0 << 11) | cb1;
    for (u32 e = tid; e < ln; e += 1024) { u32 q = (u32)(lst[e] >> 16); if ((q >> 8) == hi22) atomicAdd(&hist[q & 0xFFu], 1u); }
    __syncthreads();
    psel_full<1, 256>(hist, Kc, false, ws, sc, 2048, tid);
    u32 T0 = (hi22 << 8) | sc[0];
    u32 tiesCam = sc[1];
    if (tid == 0) scal[1] = 0;
    __syncthreads();
    for (u32 e = tid; e < ln; e += 1024) {
      u64 le = lst[e];
      if ((u32)(le >> 16) == T0) { u32 p = atomicAdd(&scal[1], 1u); if (p < 256) eqA[p] = (u32)(le & 0xFFFFu); }
    }
    __syncthreads();
    if (tid == 0) {
      u32 ne = scal[1] < 256u ? scal[1] : 256u;
      for (u32 i2 = 1; i2 < ne; i2++) { u32 v = eqA[i2]; int j = (int)i2 - 1; while (j >= 0 && eqA[j] > v) { eqA[j + 1] = eqA[j]; j--; } eqA[j + 1] = v; }
      u32 tmF = (tiesCam > 0 && tiesCam <= ne) ? eqA[tiesCam - 1] : ((tiesCam > 0) ? 0xFFFFFFFEu : 0xFFFFFFFFu);
      scal[9] = tmF;
      scal[26] = T0;
      scal[27] = tmF;
      scal[0] = 0;
    }
    __syncthreads();
    u32 tmaxF = scal[9];
    for (int c = 0; c < 64; c++) {
      int i = (c << 10) + tid; u32 q = __float_as_uint(img[i]);
      bool sel = (q < T0) || (q == T0 && tmaxF != 0xFFFFFFFFu && (u32)i <= tmaxF);
      if (sel) { u32 p = atomicAdd(&scal[0], 1u); if (p < CAP) lst[p] = ((u64)q << 16) | (u32)i; }
    }
    roi_bits(cImgW, rows, thiU, tid);
    __syncthreads();
    if (tid < 256) erode_h(rows, hrows, tid);
    __syncthreads();
    if (tid < 256) erode_v(hrows, rows, tid);
    __syncthreads();
    { u64 wv = rows[tid];
      while (wv) { int bit = __ffsll((long long)wv) - 1; wv &= wv - 1; u32 p = atomicAdd(&scal[7], 1u); if (p < FG_CAP) fgList[p] = (u64)(u32)(tid * 64 + bit); } }
    hist[tid + 2048] = 0; hist[tid + 3072] = 0;
    __syncthreads();
    listN = scal[0] < CAP ? scal[0] : CAP;
  }

  u32 T = scal[26];
  u32 camTmax = scal[27];
  u32 fgN = scal[7] < FG_CAP ? scal[7] : FG_CAP;
  if (fgN > 0) seed_generic(fgList, fgN, kf0, kf1, (u32)b, seedF, hist, eqA, scal, ws, dead, tid);

  // ---- I8a: read+filter candidates into registers
  u64 mine[8]; int nm = 0;
  for (u32 e = tid; e < listN; e += 1024) {
    u64 le = lst[e]; u32 q = (u32)(le >> 16); u32 idx = (u32)(le & 0xFFFFu);
    if (q < T || (q == T && idx <= camTmax)) { if (nm < 8) mine[nm++] = le; }
  }
  if (tid == 0) { scal[1] = 0; scal[6] = 0; }
  __syncthreads();
  // ---- I8b: compact + threefry score + bg stage1 count (4096 bins); init seeds
  {
    u32 nmU = (u32)nm;
    u32 incl = wscan_incl(nmU, lane);
    u32 wtot = __shfl(incl, 63, 64);
    u32 base2 = 0;
    if (lane == 0) base2 = atomicAdd(&scal[6], wtot);
    base2 = __shfl(base2, 0, 64);
    u32 my = base2 + incl - nmU;
    for (int k2 = 0; k2 < nm; k2++) {
      u32 idx = (u32)(mine[k2] & 0xFFFFu);
      u32 m = score_bits(kb0, kb1, ((u32)b << 16) | idx) >> 9;
      if (my + (u32)k2 < CAP) lst[my + k2] = ((u64)m << 16) | idx;
      atomicAdd(&hist[m >> 11], 1u);
    }
    seedB[tid] = 0;
    if (fgN == 0) seedF[tid] = 0;
  }
  __syncthreads();
  u32 candN = scal[6] < CAP ? scal[6] : CAP;
  u32 keff = candN < TOPK ? candN : TOPK;

  if (keff > 0) {
    // ---- I9: bg psel over 4096 bins (desc)
    u32 hb1[4], locb1 = 0, incb1 = 0;
    pselA<4, 1024>(hist, ws, tid, hb1, locb1, incb1);
    __syncthreads();
    pselB<4, 1024>(keff, true, ws, sc, tid, hb1, locb1, incb1);
    __syncthreads();
    u32 binB = sc[0], Krb = sc[1];
    // ---- I10: collect bin entries packed (invLow11<<16)|idx  (asc == m desc, idx asc)
    for (u32 e = tid; e < candN; e += 1024) {
      u64 le = lst[e]; u32 m = (u32)(le >> 16);
      if ((m >> 11) == binB) {
        u32 k2 = ((0x7FFu - (m & 0x7FFu)) << 16) | (u32)(le & 0xFFFFu);
        u32 p = atomicAdd(&scal[1], 1u); if (p < 256) eqA[p] = k2;
      }
    }
    __syncthreads();
    // ---- I11: tiny sort; rank-Krb element
    if (tid == 0) {
      u32 ne = scal[1] < 256u ? scal[1] : 256u;
      for (u32 i2 = 1; i2 < ne; i2++) { u32 v = eqA[i2]; int j = (int)i2 - 1; while (j >= 0 && eqA[j] > v) { eqA[j + 1] = eqA[j]; j--; } eqA[j + 1] = v; }
      scal[26] = eqA[Krb - 1];
    }
    __syncthreads();
    u32 key2K = scal[26];
    // ---- I12: mark
    if (!dead) {
      for (u32 e = tid; e < candN; e += 1024) {
        u64 le = lst[e]; u32 m = (u32)(le >> 16); u32 idx = (u32)(le & 0xFFFFu);
        u32 hb = m >> 11;
        u32 k2 = ((0x7FFu - (m & 0x7FFu)) << 16) | idx;
        bool sel = (hb > binB) || (hb == binB && k2 <= key2K);
        if (sel) atomicOr(&seedB[idx >> 6], 1ull << (idx & 63));
      }
    }
    __syncthreads();
  }

  // ---- dilation + conflict resolve + sparse emit (background already written)
  u64* fvL = (u64*)(arena + OFF_FVL);
  u64* bvL = (u64*)(arena + OFF_BVL);
  u64* fhL = (u64*)(arena + OFF_FHL);
  u64* bhL = (u64*)(arena + OFF_BHL);
  {
    int r = tid >> 2;
    u64 vf = seedF[tid], vb = seedB[tid];
    if (r > 0)   { vf |= seedF[tid - 4]; vb |= seedB[tid - 4]; }
    if (r < 255) { vf |= seedF[tid + 4]; vb |= seedB[tid + 4]; }
    fvL[tid] = vf; bvL[tid] = vb;
  }
  __syncthreads();
  {
    int j = tid & 3;
    u64 v = fvL[tid];
    u64 L = (j > 0) ? fvL[tid - 1] : 0ull;
    u64 R = (j < 3) ? fvL[tid + 1] : 0ull;
    fhL[tid] = v | (v << 1) | (L >> 63) | (v >> 1) | (R << 63);
    v = bvL[tid];
    L = (j > 0) ? bvL[tid - 1] : 0ull;
    R = (j < 3) ? bvL[tid + 1] : 0ull;
    bhL[tid] = v | (v << 1) | (L >> 63) | (v >> 1) | (R << 63);
  }
  __syncthreads();
  // sparse fix-up: only rewrite int4 groups with any seed-dilated bit set.
  // Ordering vs the background fill is guaranteed: multiple __syncthreads
  // (vmcnt(0) drains) separate the two writes to any address.
  for (int it = 0; it < 16; it++) {
    int idx4 = it * 1024 + tid;
    int word = idx4 >> 4;
    u64 fw = fhL[word], bw = bhL[word];
    if ((fw | bw) == 0ull) continue;
    int sh = (idx4 & 15) * 4;
    u32 fb = (u32)(fw >> sh) & 0xFu;
    u32 gb = (u32)(bw >> sh) & 0xFu;
    if ((fb | gb) == 0u) continue;
    u32 e = fb ^ gb;
    int4v o;
    o.x = (e & 1u)        ? (int)(fb & 1u)        : -255;
    o.y = ((e >> 1) & 1u) ? (int)((fb >> 1) & 1u) : -255;
    o.z = ((e >> 2) & 1u) ? (int)((fb >> 2) & 1u) : -255;
    o.w = ((e >> 3) & 1u) ? (int)((fb >> 3) & 1u) : -255;
    __builtin_nontemporal_store(o, out4 + idx4);
  }
}

extern "C" void kernel_launch(void* const* d_in, const int* in_sizes, int n_in,
                              void* d_out, int out_size, void* d_ws, size_t ws_size,
                              hipStream_t stream) {
  const float* x = (const float*)d_in[0];
  int* out = (int*)d_out;

  u32 kf0, kf1, kb0, kb1;
#if PARTITIONABLE
  threefry2x32(0u, 42u, 0u, 0u, kf0, kf1);
  threefry2x32(0u, 42u, 0u, 1u, kb0, kb1);
#else
  u32 a0, a1, c0, c1;
  threefry2x32(0u, 42u, 0u, 2u, a0, a1);
  threefry2x32(0u, 42u, 1u, 3u, c0, c1);
  kf0 = a0; kf1 = c0; kb0 = a1; kb1 = c1;
#endif

  k_all<<<BB, 1024, 0, stream>>>(x, kf0, kf1, kb0, kb1, out);
}

// Round 11
// 51.171 us; speedup vs baseline: 1.0035x; 1.0035x over previous
//
#include <hip/hip_runtime.h>
#include <stdint.h>

// MBSeederSLFCAMS — exact JAX replication; fused kernel, LDS-only barriers so
// the background emit drains in parallel with the select ladder.
#define PARTITIONABLE 1

typedef unsigned int u32;
typedef unsigned long long u64;
typedef __attribute__((ext_vector_type(4))) int int4v;

static constexpr int BB  = 256;
static constexpr int HWN = 65536;
static constexpr u32 K_BG = 6553;
static constexpr u32 TOPK = 100;
static constexpr u32 CAP  = 7936;
static constexpr u32 FG_CAP = 1024;

// ---- arena (bytes); live ranges audited per barrier interval
static constexpr int OFF_LST   = 0;        // u64[7936]  62KB  ph1..bg-mark
static constexpr int OFF_FVL   = 0;        // u64[1024]  dilate (lst dead)
static constexpr int OFF_BVL   = 8192;
static constexpr int OFF_FHL   = 16384;
static constexpr int OFF_BHL   = 24576;
static constexpr int OFF_CIMG  = 63488;    // u32[16384] 64KB  ph1..ROI
static constexpr int OFF_FGL   = 63488;    // u64[1024]  fg list (cImg dead)
static constexpr int OFF_SEEDB = 71680;    // u64[1024]
static constexpr int OFF_SEEDF = 79872;    // u64[1024]
static constexpr int OFF_HIST  = 129024;   // u32[4096]  16KB
static constexpr int OFF_HROWS = 137216;   // u64[1024]
static constexpr int OFF_ROWS  = 145408;   // u64[1024]
static constexpr int OFF_HO    = 153600;   // u32[256]
static constexpr int OFF_EQ    = 154624;   // u32[256]
static constexpr int OFF_SCAL  = 155648;   // u32[32]
static constexpr int ARENA_BYTES = 155776; // < 160 KiB

// LDS-only barrier: full producer->consumer visibility for LDS (lgkmcnt),
// does NOT drain vmcnt — in-flight global nt-stores keep draining in the
// background. Used only on the hot path, where all inter-wave communication
// is through LDS. (__syncthreads would force vmcnt(0) at every barrier.)
__device__ __forceinline__ void barl() {
  asm volatile("s_waitcnt lgkmcnt(0)\n\ts_barrier" ::: "memory");
}

__host__ __device__ inline u32 rotl32(u32 x, int d) { return (x << d) | (x >> (32 - d)); }

#define TF_ROUND(r) do { x0 += x1; x1 = rotl32(x1, r); x1 ^= x0; } while (0)

__host__ __device__ inline void threefry2x32(u32 k0, u32 k1, u32 x0, u32 x1, u32& o0, u32& o1) {
  u32 ks2 = k0 ^ k1 ^ 0x1BD11BDAu;
  x0 += k0; x1 += k1;
  TF_ROUND(13); TF_ROUND(15); TF_ROUND(26); TF_ROUND(6);
  x0 += k1;  x1 += ks2 + 1u;
  TF_ROUND(17); TF_ROUND(29); TF_ROUND(16); TF_ROUND(24);
  x0 += ks2; x1 += k0 + 2u;
  TF_ROUND(13); TF_ROUND(15); TF_ROUND(26); TF_ROUND(6);
  x0 += k0;  x1 += k1 + 3u;
  TF_ROUND(17); TF_ROUND(29); TF_ROUND(16); TF_ROUND(24);
  x0 += k1;  x1 += ks2 + 4u;
  TF_ROUND(13); TF_ROUND(15); TF_ROUND(26); TF_ROUND(6);
  x0 += ks2; x1 += k0 + 5u;
  o0 = x0; o1 = x1;
}

__device__ inline u32 score_bits(u32 k0, u32 k1, u32 i) {
#if PARTITIONABLE
  u32 a, b;
  threefry2x32(k0, k1, 0u, i, a, b);
  return a ^ b;
#else
  const u32 HALF = 1u << 23;
  u32 a, b;
  if (i < HALF) { threefry2x32(k0, k1, i, i + HALF, a, b); return a; }
  threefry2x32(k0, k1, i - HALF, i, a, b); return b;
#endif
}

__device__ __forceinline__ u32 wscan_incl(u32 v, int lane) {
#pragma unroll
  for (int d = 1; d < 64; d <<= 1) { u32 t = __shfl_up(v, d, 64); if (lane >= d) v += t; }
  return v;
}

// ---- parallel rank-select split in two halves around a barrier.
template<int BPT, int NT>
__device__ __forceinline__ void pselA(const u32* hist, u32* ws, int t, u32* h, u32& loc, u32& inc) {
  int lane = t & 63;
  loc = 0;
#pragma unroll
  for (int j = 0; j < BPT; j++) { h[j] = hist[BPT * t + j]; loc += h[j]; }
  inc = wscan_incl(loc, lane);
  if (lane == 63) ws[t >> 6] = inc;
}
template<int BPT, int NT>
__device__ __forceinline__ void pselB(u32 K, bool desc, const u32* ws, u32* sc, int t, const u32* h, u32 loc, u32 inc) {
  const int NW = NT / 64;
  int wid = t >> 6;
  u32 off = 0, total = 0;
#pragma unroll
  for (int k = 0; k < NW; k++) { u32 wv = ws[k]; total += wv; if (k < wid) off += wv; }
  inc += off;
  if (!desc) {
    u32 ex = inc - loc;
#pragma unroll
    for (int j = 0; j < BPT; j++) { if (ex < K && K <= ex + h[j]) { sc[0] = BPT * t + j; sc[1] = K - ex; } ex += h[j]; }
  } else {
    u32 ex = total - inc;
#pragma unroll
    for (int j = BPT - 1; j >= 0; j--) { if (ex < K && K <= ex + h[j]) { sc[0] = BPT * t + j; sc[1] = K - ex; } ex += h[j]; }
  }
}

// ---- full psel with internal barriers (cold paths only); zeroes hist[0..zeroN)
template<int BPT, int NT>
__device__ void psel_full(u32* hist, u32 K, bool desc, u32* ws, u32* sc, int zeroN, int tid) {
  u32 h[BPT], loc = 0, inc = 0;
  bool act = tid < NT;
  if (act) pselA<BPT, NT>(hist, ws, tid, h, loc, inc);
  __syncthreads();
  if (act) pselB<BPT, NT>(K, desc, ws, sc, tid, h, loc, inc);
  for (int k = tid; k < zeroN; k += 1024) hist[k] = 0;
  __syncthreads();
}

// ---- register-only Otsu on wave 0 (no barriers). Writes scal[8]=thi, scal[5]=bad.
__device__ __forceinline__ void otsu_wave0(const u32* hO, u32* scal, int lane) {
  u32 base = (u32)lane * 4;
  u32 h[4], cw[4], cs[4];
#pragma unroll
  for (int j = 0; j < 4; j++) h[j] = hO[base + j];
  cw[0] = h[0]; cs[0] = h[0] * base;
#pragma unroll
  for (int j = 1; j < 4; j++) { cw[j] = cw[j-1] + h[j]; cs[j] = cs[j-1] + h[j] * (base + j); }
  u32 incW = wscan_incl(cw[3], lane);
  u32 incS = wscan_incl(cs[3], lane);
  u32 offW = incW - cw[3], offS = incS - cs[3];
  u32 totW = __shfl(incW, 63, 64), totS = __shfl(incS, 63, 64);
  int nz = 0;
#pragma unroll
  for (int j = 0; j < 4; j++) nz += (h[j] != 0);
#pragma unroll
  for (int d = 1; d < 64; d <<= 1) nz += __shfl_xor(nz, d, 64);
  u32 selfW0 = cw[0] + offW, selfS0 = cs[0] + offS;
  u32 nxtW = __shfl_down(selfW0, 1, 64);
  u32 nxtS = __shfl_down(selfS0, 1, 64);
  u32 nxtH = __shfl_down(h[0], 1, 64);
  float total = (float)totW, stot = (float)totS;
  unsigned long long best = 0ull;
#pragma unroll
  for (int j = 0; j < 4; j++) {
    int t = (int)base + j;
    if (t < 255) {
      float h1 = (float)((j < 3) ? h[j+1] : nxtH);
      float w1 = (float)(cw[j] + offW);
      float w1n = (j < 3) ? (float)(cw[j+1] + offW) : (float)nxtW;
      float s1 = (float)(cs[j] + offS);
      float s1n = (j < 3) ? (float)(cs[j+1] + offS) : (float)nxtS;
      float w2 = total - w1n + h1;
      float s2 = stot - s1n + h1 * (float)(t + 1);
      float m1 = s1 / fmaxf(w1, 1.0f);
      float m2 = s2 / fmaxf(w2, 1.0f);
      float d = m1 - m2;
      float v = (w1 * w2) * (d * d);
      unsigned long long key = ((unsigned long long)__float_as_uint(v) << 32) | (u32)(255 - t);
      if (key > best) best = key;
    }
  }
#pragma unroll
  for (int d = 1; d < 64; d <<= 1) { unsigned long long o = __shfl_xor(best, d, 64); if (o > best) best = o; }
  if (lane == 0) {
    int bi = 255 - (int)(best & 0xFFFFFFFFu);
    float th = (float)bi;
    th = (th <= 0.0f) ? 1.0f : ((th >= 255.0f) ? 254.0f : th);
    scal[8] = (u32)(int)th;
    scal[5] = (nz <= 1) ? 1u : 0u;
  }
}

__device__ __forceinline__ void roi_bits(const u32* cImgW, u64* rows, u32 thiU, int tid) {
  u64 bits = 0;
#pragma unroll
  for (int k2 = 0; k2 < 16; k2++) {
    int k = (k2 + (tid >> 1)) & 15;
    u32 v4 = cImgW[tid * 16 + k];
    u32 m = 0;
    if ((v4 & 0xFFu) > thiU)         m |= 1u;
    if (((v4 >> 8) & 0xFFu) > thiU)  m |= 2u;
    if (((v4 >> 16) & 0xFFu) > thiU) m |= 4u;
    if ((v4 >> 24) > thiU)           m |= 8u;
    bits |= (u64)m << (4 * k);
  }
  rows[tid] = bits;
}

__device__ __forceinline__ void erode_h(const u64* rows, u64* hrows, int r) {
  u64 wv[4], h0[4];
  for (int j = 0; j < 4; j++) { wv[j] = rows[r * 4 + j]; h0[j] = wv[j]; }
  for (int s = 1; s <= 5; s++)
    for (int j = 0; j < 4; j++) {
      u64 hi = (j < 3) ? wv[j + 1] : ~0ull;
      u64 lo = (j > 0) ? wv[j - 1] : ~0ull;
      h0[j] &= ((wv[j] >> s) | (hi << (64 - s))) & ((wv[j] << s) | (lo >> (64 - s)));
    }
  for (int j = 0; j < 4; j++) hrows[r * 4 + j] = h0[j];
}

__device__ __forceinline__ void erode_v(const u64* hrows, u64* rows, int r) {
  u64 res[4] = {hrows[r * 4], hrows[r * 4 + 1], hrows[r * 4 + 2], hrows[r * 4 + 3]};
  for (int dr = -5; dr <= 5; dr++) {
    if (dr == 0) continue;
    int rr = r + dr;
    if (rr < 0 || rr >= 256) continue;
    for (int j = 0; j < 4; j++) res[j] &= hrows[rr * 4 + j];
  }
  for (int j = 0; j < 4; j++) rows[r * 4 + j] = res[j];
}

// ---- generic top-100 seeding from an idx list (cold fg path; full barriers).
__device__ void seed_generic(u64* lst2, u32 n, u32 k0, u32 k1, u32 bimg, u64* seedRows,
                             u32* hist, u32* eqA, u32* scal, u32* ws, bool dead, int tid) {
  u32* sc = scal + 2;
  seedRows[tid] = 0;
  for (u32 e = tid; e < n; e += 1024) {
    u32 idx = (u32)(lst2[e] & 0xFFFFu);
    u32 m = score_bits(k0, k1, (bimg << 16) | idx) >> 9;
    lst2[e] = ((u64)m << 16) | idx;
    atomicAdd(&hist[m >> 12], 1u);
  }
  if (tid == 0) scal[1] = 0;
  __syncthreads();
  u32 keff = n < TOPK ? n : TOPK;
  psel_full<2, 1024>(hist, keff, true, ws, sc, 4096, tid);
  u32 s0 = sc[0], Kr = sc[1];
  for (u32 e = tid; e < n; e += 1024) { u32 m = (u32)(lst2[e] >> 16); if ((m >> 12) == s0) atomicAdd(&hist[m & 0xFFFu], 1u); }
  __syncthreads();
  psel_full<4, 1024>(hist, Kr, true, ws, sc, 4096, tid);
  u32 S = (s0 << 12) | sc[0]; u32 tiesS = sc[1];
  for (u32 e = tid; e < n; e += 1024) {
    u64 le = lst2[e]; u32 m = (u32)(le >> 16); u32 idx = (u32)(le & 0xFFFFu);
    if (m > S) { if (!dead) atomicOr(&seedRows[idx >> 6], 1ull << (idx & 63)); }
    else if (m == S) { u32 p = atomicAdd(&scal[1], 1u); if (p < 256) eqA[p] = idx; }
  }
  __syncthreads();
  if (tid == 0) {
    u32 ne = scal[1] < 256u ? scal[1] : 256u;
    for (u32 i2 = 1; i2 < ne; i2++) { u32 v = eqA[i2]; int j = (int)i2 - 1; while (j >= 0 && eqA[j] > v) { eqA[j + 1] = eqA[j]; j--; } eqA[j + 1] = v; }
    scal[4] = ne;
  }
  __syncthreads();
  { u32 ne = scal[4]; u32 tk = tiesS < ne ? tiesS : ne;
    if (!dead && (u32)tid < tk) { u32 idx = eqA[tid]; atomicOr(&seedRows[idx >> 6], 1ull << (idx & 63)); } }
  __syncthreads();
}

__global__ __launch_bounds__(1024, 4) void k_all(const float* __restrict__ x,
                                                 u32 kf0, u32 kf1, u32 kb0, u32 kb1,
                                                 int* __restrict__ out) {
  __shared__ __align__(16) char arena[ARENA_BYTES];
  const int b = blockIdx.x, tid = threadIdx.x;
  const int lane = tid & 63;

  u64* lst    = (u64*)(arena + OFF_LST);
  u32* cImgW  = (u32*)(arena + OFF_CIMG);
  u32* hO     = (u32*)(arena + OFF_HO);
  u32* hist   = (u32*)(arena + OFF_HIST);
  u32* eqA    = (u32*)(arena + OFF_EQ);
  u32* scal   = (u32*)(arena + OFF_SCAL);
  u32* ws     = scal + 10;
  u32* sc     = scal + 2;
  u64* rows   = (u64*)(arena + OFF_ROWS);
  u64* hrows  = (u64*)(arena + OFF_HROWS);
  u64* fgList = (u64*)(arena + OFF_FGL);
  u64* seedB  = (u64*)(arena + OFF_SEEDB);
  u64* seedF  = (u64*)(arena + OFF_SEEDF);

  const u32 BND = __float_as_uint(0.110f);
  const float4* img4 = (const float4*)(x + (size_t)b * HWN);
  const float* img = x + (size_t)b * HWN;
  int4v* out4 = (int4v*)(out + (size_t)b * HWN);

  // ---- I0: zero
  if (tid < 256) hO[tid] = 0;
  hist[tid] = 0; hist[tid + 1024] = 0;
  if (tid < 10) scal[tid] = 0;
  __syncthreads();

  // ---- I1: single scan: cImg pack, otsu hist, cam-stage1 count, scan-based push
#pragma unroll
  for (int half = 0; half < 2; ++half) {
    float4 v[8];
#pragma unroll
    for (int k = 0; k < 8; k++) v[k] = img4[((half * 8 + k) << 10) + tid];
    u32 nq = 0;
#pragma unroll
    for (int k = 0; k < 8; k++) {
      u32 c0 = (u32)(int)(v[k].x * 255.0f);
      u32 c1 = (u32)(int)(v[k].y * 255.0f);
      u32 c2 = (u32)(int)(v[k].z * 255.0f);
      u32 c3 = (u32)(int)(v[k].w * 255.0f);
      atomicAdd(&hO[c0], 1u); atomicAdd(&hO[c1], 1u);
      atomicAdd(&hO[c2], 1u); atomicAdd(&hO[c3], 1u);
      cImgW[((half * 8 + k) << 10) + tid] = c0 | (c1 << 8) | (c2 << 16) | (c3 << 24);
      u32 q0 = __float_as_uint(v[k].x), q1 = __float_as_uint(v[k].y);
      u32 q2 = __float_as_uint(v[k].z), q3 = __float_as_uint(v[k].w);
      if (q0 < BND) { nq++; atomicAdd(&hist[q0 >> 19], 1u); }
      if (q1 < BND) { nq++; atomicAdd(&hist[q1 >> 19], 1u); }
      if (q2 < BND) { nq++; atomicAdd(&hist[q2 >> 19], 1u); }
      if (q3 < BND) { nq++; atomicAdd(&hist[q3 >> 19], 1u); }
    }
    u32 incl = wscan_incl(nq, lane);
    u32 wtot = __shfl(incl, 63, 64);
    u32 base = 0;
    if (lane == 0) base = atomicAdd(&scal[0], wtot);
    base = __shfl(base, 0, 64);
    u32 pos = base + incl - nq;
#pragma unroll
    for (int k = 0; k < 8; k++) {
      u32 q0 = __float_as_uint(v[k].x), q1 = __float_as_uint(v[k].y);
      u32 q2 = __float_as_uint(v[k].z), q3 = __float_as_uint(v[k].w);
      u32 pix = (u32)((((half * 8 + k) << 10) + tid) * 4);
      if (q0 < BND) { if (pos < CAP) lst[pos] = ((u64)q0 << 16) | pix; pos++; }
      if (q1 < BND) { if (pos < CAP) lst[pos] = ((u64)q1 << 16) | (pix + 1); pos++; }
      if (q2 < BND) { if (pos < CAP) lst[pos] = ((u64)q2 << 16) | (pix + 2); pos++; }
      if (q3 < BND) { if (pos < CAP) lst[pos] = ((u64)q3 << 16) | (pix + 3); pos++; }
    }
  }
  __syncthreads();
  u32 cntBelow = scal[0];
  bool fastOK = (cntBelow >= K_BG && cntBelow <= CAP);

  // ---- background fill: entire image = -255 via nt stores. With LDS-only
  // barriers below, these stores drain through the write pipe in parallel
  // with the select ladder. The sparse fix-up at the end waits vmcnt(0)
  // (per-thread; same thread rewrites the same addresses) before rewriting.
  {
    int4v neg; neg.x = -255; neg.y = -255; neg.z = -255; neg.w = -255;
#pragma unroll
    for (int it = 0; it < 16; it++)
      __builtin_nontemporal_store(neg, out4 + it * 1024 + tid);
  }

  // ---- I2a: Otsu (wave 0) ∥ cam psel stage1 scan (tid>=512)
  {
    u32 h1v[4], loc1 = 0, inc1 = 0;
    if (tid < 64) otsu_wave0(hO, scal, lane);
    if (tid >= 512) pselA<4, 512>(hist, ws, tid - 512, h1v, loc1, inc1);
    barl();
    // ---- I2b: psel stage1 finish ∥ zero hist[0..2047] (tid<512)
    if (tid >= 512) pselB<4, 512>(K_BG, false, ws, sc, tid - 512, h1v, loc1, inc1);
    else { hist[tid*4] = 0; hist[tid*4+1] = 0; hist[tid*4+2] = 0; hist[tid*4+3] = 0; }
    barl();
  }
  u32 thiU = scal[8];
  bool dead = scal[5] != 0u;

  u32 listN;
  if (fastOK) {
    listN = cntBelow;
    u32 cb0 = sc[0], Kb = sc[1];
    // ---- I4: stage2 count ∥ ROI bits
    for (u32 e = tid; e < listN; e += 1024) { u32 q = (u32)(lst[e] >> 16); if ((q >> 19) == cb0) atomicAdd(&hist[(q >> 8) & 0x7FFu], 1u); }
    roi_bits(cImgW, rows, thiU, tid);
    barl();
    // ---- I5a: psel stage2 scan (tid<512) ∥ erosion-h (512..767)
    u32 h2v[4], loc2 = 0, inc2 = 0;
    if (tid < 512) pselA<4, 512>(hist, ws, tid, h2v, loc2, inc2);
    else if (tid < 768) erode_h(rows, hrows, tid - 512);
    barl();
    // ---- I5b: psel stage2 finish ∥ erosion-v (512..767)
    if (tid < 512) pselB<4, 512>(Kb, false, ws, sc, tid, h2v, loc2, inc2);
    else if (tid < 768) erode_v(hrows, rows, tid - 512);
    barl();
    u32 cb1 = sc[0], Kc = sc[1];
    u32 hi22 = (cb0 << 11) | cb1;
    // ---- I6: collect stage3-bin entries ∥ fg extract ∥ zero hist[0..4095]
    for (u32 e = tid; e < listN; e += 1024) {
      u64 le = lst[e]; u32 q = (u32)(le >> 16);
      if ((q >> 8) == hi22) { u32 p = atomicAdd(&scal[1], 1u); if (p < 256) eqA[p] = ((q & 0xFFu) << 16) | (u32)(le & 0xFFFFu); }
    }
    { u64 wv = rows[tid];
      while (wv) { int bit = __ffsll((long long)wv) - 1; wv &= wv - 1; u32 p = atomicAdd(&scal[7], 1u); if (p < FG_CAP) fgList[p] = (u64)(u32)(tid * 64 + bit); } }
    hist[tid] = 0; hist[tid + 1024] = 0; hist[tid + 2048] = 0; hist[tid + 3072] = 0;
    barl();
    // ---- I7: exact finish — sort bin entries asc by (low8, idx); rank-Kc element
    if (tid == 0) {
      u32 ne = scal[1] < 256u ? scal[1] : 256u;
      for (u32 i2 = 1; i2 < ne; i2++) { u32 v = eqA[i2]; int j = (int)i2 - 1; while (j >= 0 && eqA[j] > v) { eqA[j + 1] = eqA[j]; j--; } eqA[j + 1] = v; }
      u32 ent = eqA[Kc - 1];
      scal[26] = (hi22 << 8) | (ent >> 16);   // T (full float bits)
      scal[27] = ent & 0xFFFFu;               // tie-max idx at T
    }
    barl();
  } else {
    // ======== cold exact fallback: full-range recount from global ========
    for (int k2 = tid; k2 < 4096; k2 += 1024) hist[k2] = 0;
    __syncthreads();
    for (int c = 0; c < 64; c++) atomicAdd(&hist[__float_as_uint(img[(c << 10) + tid]) >> 19], 1u);
    __syncthreads();
    psel_full<2, 1024>(hist, K_BG, false, ws, sc, 2048, tid);
    u32 cb0 = sc[0], Kb = sc[1];
    if (tid == 0) scal[0] = 0;
    __syncthreads();
    for (int c = 0; c < 64; c++) {
      int i = (c << 10) + tid; u32 q = __float_as_uint(img[i]);
      if ((q >> 19) == cb0) { u32 p = atomicAdd(&scal[0], 1u); if (p < CAP) lst[p] = ((u64)q << 16) | (u32)i; }
    }
    __syncthreads();
    u32 ln = scal[0] < CAP ? scal[0] : CAP;
    for (u32 e = tid; e < ln; e += 1024) { u32 q = (u32)(lst[e] >> 16); atomicAdd(&hist[(q >> 8) & 0x7FFu], 1u); }
    __syncthreads();
    psel_full<2, 1024>(hist, Kb, false, ws, sc, 256, tid);
    u32 cb1 = sc[0], Kc = sc[1];
    u32 hi22 = (cb0 << 11) | cb1;
    for (u32 e = tid; e < ln; e += 1024) { u32 q = (u32)(lst[e] >> 16); if ((q >> 8) == hi22) atomicAdd(&hist[q & 0xFFu], 1u); }
    __syncthreads();
    psel_full<1, 256>(hist, Kc, false, ws, sc, 2048, tid);
    u32 T0 = (hi22 << 8) | sc[0];
    u32 tiesCam = sc[1];
    if (tid == 0) scal[1] = 0;
    __syncthreads();
    for (u32 e = tid; e < ln; e += 1024) {
      u64 le = lst[e];
      if ((u32)(le >> 16) == T0) { u32 p = atomicAdd(&scal[1], 1u); if (p < 256) eqA[p] = (u32)(le & 0xFFFFu); }
    }
    __syncthreads();
    if (tid == 0) {
      u32 ne = scal[1] < 256u ? scal[1] : 256u;
      for (u32 i2 = 1; i2 < ne; i2++) { u32 v = eqA[i2]; int j = (int)i2 - 1; while (j >= 0 && eqA[j] > v) { eqA[j + 1] = eqA[j]; j--; } eqA[j + 1] = v; }
      u32 tmF = (tiesCam > 0 && tiesCam <= ne) ? eqA[tiesCam - 1] : ((tiesCam > 0) ? 0xFFFFFFFEu : 0xFFFFFFFFu);
      scal[9] = tmF;
      scal[26] = T0;
      scal[27] = tmF;
      scal[0] = 0;
    }
    __syncthreads();
    u32 tmaxF = scal[9];
    for (int c = 0; c < 64; c++) {
      int i = (c << 10) + tid; u32 q = __float_as_uint(img[i]);
      bool sel = (q < T0) || (q == T0 && tmaxF != 0xFFFFFFFFu && (u32)i <= tmaxF);
      if (sel) { u32 p = atomicAdd(&scal[0], 1u); if (p < CAP) lst[p] = ((u64)q << 16) | (u32)i; }
    }
    roi_bits(cImgW, rows, thiU, tid);
    __syncthreads();
    if (tid < 256) erode_h(rows, hrows, tid);
    __syncthreads();
    if (tid < 256) erode_v(hrows, rows, tid);
    __syncthreads();
    { u64 wv = rows[tid];
      while (wv) { int bit = __ffsll((long long)wv) - 1; wv &= wv - 1; u32 p = atomicAdd(&scal[7], 1u); if (p < FG_CAP) fgList[p] = (u64)(u32)(tid * 64 + bit); } }
    hist[tid + 2048] = 0; hist[tid + 3072] = 0;
    __syncthreads();
    listN = scal[0] < CAP ? scal[0] : CAP;
  }

  u32 T = scal[26];
  u32 camTmax = scal[27];
  u32 fgN = scal[7] < FG_CAP ? scal[7] : FG_CAP;
  if (fgN > 0) seed_generic(fgList, fgN, kf0, kf1, (u32)b, seedF, hist, eqA, scal, ws, dead, tid);

  // ---- I8a: read+filter candidates into registers
  u64 mine[8]; int nm = 0;
  for (u32 e = tid; e < listN; e += 1024) {
    u64 le = lst[e]; u32 q = (u32)(le >> 16); u32 idx = (u32)(le & 0xFFFFu);
    if (q < T || (q == T && idx <= camTmax)) { if (nm < 8) mine[nm++] = le; }
  }
  if (tid == 0) { scal[1] = 0; scal[6] = 0; }
  barl();
  // ---- I8b: compact + threefry score + bg stage1 count (4096 bins); init seeds
  {
    u32 nmU = (u32)nm;
    u32 incl = wscan_incl(nmU, lane);
    u32 wtot = __shfl(incl, 63, 64);
    u32 base2 = 0;
    if (lane == 0) base2 = atomicAdd(&scal[6], wtot);
    base2 = __shfl(base2, 0, 64);
    u32 my = base2 + incl - nmU;
    for (int k2 = 0; k2 < nm; k2++) {
      u32 idx = (u32)(mine[k2] & 0xFFFFu);
      u32 m = score_bits(kb0, kb1, ((u32)b << 16) | idx) >> 9;
      if (my + (u32)k2 < CAP) lst[my + k2] = ((u64)m << 16) | idx;
      atomicAdd(&hist[m >> 11], 1u);
    }
    seedB[tid] = 0;
    if (fgN == 0) seedF[tid] = 0;
  }
  barl();
  u32 candN = scal[6] < CAP ? scal[6] : CAP;
  u32 keff = candN < TOPK ? candN : TOPK;

  if (keff > 0) {
    // ---- I9: bg psel over 4096 bins (desc)
    u32 hb1[4], locb1 = 0, incb1 = 0;
    pselA<4, 1024>(hist, ws, tid, hb1, locb1, incb1);
    barl();
    pselB<4, 1024>(keff, true, ws, sc, tid, hb1, locb1, incb1);
    barl();
    u32 binB = sc[0], Krb = sc[1];
    // ---- I10: collect bin entries packed (invLow11<<16)|idx  (asc == m desc, idx asc)
    for (u32 e = tid; e < candN; e += 1024) {
      u64 le = lst[e]; u32 m = (u32)(le >> 16);
      if ((m >> 11) == binB) {
        u32 k2 = ((0x7FFu - (m & 0x7FFu)) << 16) | (u32)(le & 0xFFFFu);
        u32 p = atomicAdd(&scal[1], 1u); if (p < 256) eqA[p] = k2;
      }
    }
    barl();
    // ---- I11: tiny sort; rank-Krb element
    if (tid == 0) {
      u32 ne = scal[1] < 256u ? scal[1] : 256u;
      for (u32 i2 = 1; i2 < ne; i2++) { u32 v = eqA[i2]; int j = (int)i2 - 1; while (j >= 0 && eqA[j] > v) { eqA[j + 1] = eqA[j]; j--; } eqA[j + 1] = v; }
      scal[26] = eqA[Krb - 1];
    }
    barl();
    u32 key2K = scal[26];
    // ---- I12: mark
    if (!dead) {
      for (u32 e = tid; e < candN; e += 1024) {
        u64 le = lst[e]; u32 m = (u32)(le >> 16); u32 idx = (u32)(le & 0xFFFFu);
        u32 hb = m >> 11;
        u32 k2 = ((0x7FFu - (m & 0x7FFu)) << 16) | idx;
        bool sel = (hb > binB) || (hb == binB && k2 <= key2K);
        if (sel) atomicOr(&seedB[idx >> 6], 1ull << (idx & 63));
      }
    }
    barl();
  }

  // ---- dilation + conflict resolve + sparse emit (background already written)
  u64* fvL = (u64*)(arena + OFF_FVL);
  u64* bvL = (u64*)(arena + OFF_BVL);
  u64* fhL = (u64*)(arena + OFF_FHL);
  u64* bhL = (u64*)(arena + OFF_BHL);
  {
    int r = tid >> 2;
    u64 vf = seedF[tid], vb = seedB[tid];
    if (r > 0)   { vf |= seedF[tid - 4]; vb |= seedB[tid - 4]; }
    if (r < 255) { vf |= seedF[tid + 4]; vb |= seedB[tid + 4]; }
    fvL[tid] = vf; bvL[tid] = vb;
  }
  barl();
  {
    int j = tid & 3;
    u64 v = fvL[tid];
    u64 L = (j > 0) ? fvL[tid - 1] : 0ull;
    u64 R = (j < 3) ? fvL[tid + 1] : 0ull;
    fhL[tid] = v | (v << 1) | (L >> 63) | (v >> 1) | (R << 63);
    v = bvL[tid];
    L = (j > 0) ? bvL[tid - 1] : 0ull;
    R = (j < 3) ? bvL[tid + 1] : 0ull;
    bhL[tid] = v | (v << 1) | (L >> 63) | (v >> 1) | (R << 63);
  }
  barl();
  // Per-thread drain of own background-fill stores (long since completed —
  // they had the whole ladder to drain). Same thread rewrites the same
  // addresses, so per-wave vmcnt(0) ordering is sufficient.
  asm volatile("s_waitcnt vmcnt(0)" ::: "memory");
  for (int it = 0; it < 16; it++) {
    int idx4 = it * 1024 + tid;
    int word = idx4 >> 4;
    u64 fw = fhL[word], bw = bhL[word];
    if ((fw | bw) == 0ull) continue;
    int sh = (idx4 & 15) * 4;
    u32 fb = (u32)(fw >> sh) & 0xFu;
    u32 gb = (u32)(bw >> sh) & 0xFu;
    if ((fb | gb) == 0u) continue;
    u32 e = fb ^ gb;
    int4v o;
    o.x = (e & 1u)        ? (int)(fb & 1u)        : -255;
    o.y = ((e >> 1) & 1u) ? (int)((fb >> 1) & 1u) : -255;
    o.z = ((e >> 2) & 1u) ? (int)((fb >> 2) & 1u) : -255;
    o.w = ((e >> 3) & 1u) ? (int)((fb >> 3) & 1u) : -255;
    __builtin_nontemporal_store(o, out4 + idx4);
  }
}

extern "C" void kernel_launch(void* const* d_in, const int* in_sizes, int n_in,
                              void* d_out, int out_size, void* d_ws, size_t ws_size,
                              hipStream_t stream) {
  const float* x = (const float*)d_in[0];
  int* out = (int*)d_out;

  u32 kf0, kf1, kb0, kb1;
#if PARTITIONABLE
  threefry2x32(0u, 42u, 0u, 0u, kf0, kf1);
  threefry2x32(0u, 42u, 0u, 1u, kb0, kb1);
#else
  u32 a0, a1, c0, c1;
  threefry2x32(0u, 42u, 0u, 2u, a0, a1);
  threefry2x32(0u, 42u, 1u, 3u, c0, c1);
  kf0 = a0; kf1 = c0; kb0 = a1; kb1 = c1;
#endif

  k_all<<<BB, 1024, 0, stream>>>(x, kf0, kf1, kb0, kb1, out);
}

// Round 12
// 48.648 us; speedup vs baseline: 1.0555x; 1.0519x over previous
//
#include <hip/hip_runtime.h>
#include <stdint.h>

// MBSeederSLFCAMS — exact JAX replication; fused kernel (round-9 structure)
// + 4-way privatized Otsu histogram to cut LDS atomic contention.
#define PARTITIONABLE 1

typedef unsigned int u32;
typedef unsigned long long u64;
typedef __attribute__((ext_vector_type(4))) int int4v;

static constexpr int BB  = 256;
static constexpr int HWN = 65536;
static constexpr u32 K_BG = 6553;
static constexpr u32 TOPK = 100;
static constexpr u32 CAP  = 7936;
static constexpr u32 FG_CAP = 1024;

// ---- arena (bytes); live ranges audited per barrier interval
static constexpr int OFF_LST   = 0;        // u64[7936]  62KB  ph1..bg-mark
static constexpr int OFF_FVL   = 0;        // u64[1024]  dilate (lst dead)
static constexpr int OFF_BVL   = 8192;
static constexpr int OFF_FHL   = 16384;
static constexpr int OFF_BHL   = 24576;
static constexpr int OFF_CIMG  = 63488;    // u32[16384] 64KB  ph1..ROI
static constexpr int OFF_FGL   = 63488;    // u64[1024]  fg list (cImg dead)
static constexpr int OFF_SEEDB = 71680;    // u64[1024]
static constexpr int OFF_SEEDF = 79872;    // u64[1024]
static constexpr int OFF_HIST  = 129024;   // u32[4096]  16KB
static constexpr int OFF_HROWS = 137216;   // u64[1024]
static constexpr int OFF_ROWS  = 145408;   // u64[1024]
static constexpr int OFF_HO4   = 153600;   // u32[4*264] 4.125KB (4 padded copies)
static constexpr int OFF_EQ    = 157824;   // u32[256]
static constexpr int OFF_SCAL  = 158848;   // u32[32]
static constexpr int ARENA_BYTES = 158976; // < 160 KiB

__host__ __device__ inline u32 rotl32(u32 x, int d) { return (x << d) | (x >> (32 - d)); }

#define TF_ROUND(r) do { x0 += x1; x1 = rotl32(x1, r); x1 ^= x0; } while (0)

__host__ __device__ inline void threefry2x32(u32 k0, u32 k1, u32 x0, u32 x1, u32& o0, u32& o1) {
  u32 ks2 = k0 ^ k1 ^ 0x1BD11BDAu;
  x0 += k0; x1 += k1;
  TF_ROUND(13); TF_ROUND(15); TF_ROUND(26); TF_ROUND(6);
  x0 += k1;  x1 += ks2 + 1u;
  TF_ROUND(17); TF_ROUND(29); TF_ROUND(16); TF_ROUND(24);
  x0 += ks2; x1 += k0 + 2u;
  TF_ROUND(13); TF_ROUND(15); TF_ROUND(26); TF_ROUND(6);
  x0 += k0;  x1 += k1 + 3u;
  TF_ROUND(17); TF_ROUND(29); TF_ROUND(16); TF_ROUND(24);
  x0 += k1;  x1 += ks2 + 4u;
  TF_ROUND(13); TF_ROUND(15); TF_ROUND(26); TF_ROUND(6);
  x0 += ks2; x1 += k0 + 5u;
  o0 = x0; o1 = x1;
}

__device__ inline u32 score_bits(u32 k0, u32 k1, u32 i) {
#if PARTITIONABLE
  u32 a, b;
  threefry2x32(k0, k1, 0u, i, a, b);
  return a ^ b;
#else
  const u32 HALF = 1u << 23;
  u32 a, b;
  if (i < HALF) { threefry2x32(k0, k1, i, i + HALF, a, b); return a; }
  threefry2x32(k0, k1, i - HALF, i, a, b); return b;
#endif
}

__device__ __forceinline__ u32 wscan_incl(u32 v, int lane) {
#pragma unroll
  for (int d = 1; d < 64; d <<= 1) { u32 t = __shfl_up(v, d, 64); if (lane >= d) v += t; }
  return v;
}

// ---- parallel rank-select split in two halves around a barrier.
template<int BPT, int NT>
__device__ __forceinline__ void pselA(const u32* hist, u32* ws, int t, u32* h, u32& loc, u32& inc) {
  int lane = t & 63;
  loc = 0;
#pragma unroll
  for (int j = 0; j < BPT; j++) { h[j] = hist[BPT * t + j]; loc += h[j]; }
  inc = wscan_incl(loc, lane);
  if (lane == 63) ws[t >> 6] = inc;
}
template<int BPT, int NT>
__device__ __forceinline__ void pselB(u32 K, bool desc, const u32* ws, u32* sc, int t, const u32* h, u32 loc, u32 inc) {
  const int NW = NT / 64;
  int wid = t >> 6;
  u32 off = 0, total = 0;
#pragma unroll
  for (int k = 0; k < NW; k++) { u32 wv = ws[k]; total += wv; if (k < wid) off += wv; }
  inc += off;
  if (!desc) {
    u32 ex = inc - loc;
#pragma unroll
    for (int j = 0; j < BPT; j++) { if (ex < K && K <= ex + h[j]) { sc[0] = BPT * t + j; sc[1] = K - ex; } ex += h[j]; }
  } else {
    u32 ex = total - inc;
#pragma unroll
    for (int j = BPT - 1; j >= 0; j--) { if (ex < K && K <= ex + h[j]) { sc[0] = BPT * t + j; sc[1] = K - ex; } ex += h[j]; }
  }
}

// ---- full psel with internal barriers (cold paths); zeroes hist[0..zeroN)
template<int BPT, int NT>
__device__ void psel_full(u32* hist, u32 K, bool desc, u32* ws, u32* sc, int zeroN, int tid) {
  u32 h[BPT], loc = 0, inc = 0;
  bool act = tid < NT;
  if (act) pselA<BPT, NT>(hist, ws, tid, h, loc, inc);
  __syncthreads();
  if (act) pselB<BPT, NT>(K, desc, ws, sc, tid, h, loc, inc);
  for (int k = tid; k < zeroN; k += 1024) hist[k] = 0;
  __syncthreads();
}

// ---- register-only Otsu on wave 0 (no barriers); reads 4 privatized copies.
__device__ __forceinline__ void otsu_wave0(const u32* hO4, u32* scal, int lane) {
  u32 base = (u32)lane * 4;
  u32 h[4], cw[4], cs[4];
#pragma unroll
  for (int j = 0; j < 4; j++)
    h[j] = hO4[base + j] + hO4[264 + base + j] + hO4[528 + base + j] + hO4[792 + base + j];
  cw[0] = h[0]; cs[0] = h[0] * base;
#pragma unroll
  for (int j = 1; j < 4; j++) { cw[j] = cw[j-1] + h[j]; cs[j] = cs[j-1] + h[j] * (base + j); }
  u32 incW = wscan_incl(cw[3], lane);
  u32 incS = wscan_incl(cs[3], lane);
  u32 offW = incW - cw[3], offS = incS - cs[3];
  u32 totW = __shfl(incW, 63, 64), totS = __shfl(incS, 63, 64);
  int nz = 0;
#pragma unroll
  for (int j = 0; j < 4; j++) nz += (h[j] != 0);
#pragma unroll
  for (int d = 1; d < 64; d <<= 1) nz += __shfl_xor(nz, d, 64);
  u32 selfW0 = cw[0] + offW, selfS0 = cs[0] + offS;
  u32 nxtW = __shfl_down(selfW0, 1, 64);
  u32 nxtS = __shfl_down(selfS0, 1, 64);
  u32 nxtH = __shfl_down(h[0], 1, 64);
  float total = (float)totW, stot = (float)totS;
  unsigned long long best = 0ull;
#pragma unroll
  for (int j = 0; j < 4; j++) {
    int t = (int)base + j;
    if (t < 255) {
      float h1 = (float)((j < 3) ? h[j+1] : nxtH);
      float w1 = (float)(cw[j] + offW);
      float w1n = (j < 3) ? (float)(cw[j+1] + offW) : (float)nxtW;
      float s1 = (float)(cs[j] + offS);
      float s1n = (j < 3) ? (float)(cs[j+1] + offS) : (float)nxtS;
      float w2 = total - w1n + h1;
      float s2 = stot - s1n + h1 * (float)(t + 1);
      float m1 = s1 / fmaxf(w1, 1.0f);
      float m2 = s2 / fmaxf(w2, 1.0f);
      float d = m1 - m2;
      float v = (w1 * w2) * (d * d);
      unsigned long long key = ((unsigned long long)__float_as_uint(v) << 32) | (u32)(255 - t);
      if (key > best) best = key;
    }
  }
#pragma unroll
  for (int d = 1; d < 64; d <<= 1) { unsigned long long o = __shfl_xor(best, d, 64); if (o > best) best = o; }
  if (lane == 0) {
    int bi = 255 - (int)(best & 0xFFFFFFFFu);
    float th = (float)bi;
    th = (th <= 0.0f) ? 1.0f : ((th >= 255.0f) ? 254.0f : th);
    scal[8] = (u32)(int)th;
    scal[5] = (nz <= 1) ? 1u : 0u;
  }
}

__device__ __forceinline__ void roi_bits(const u32* cImgW, u64* rows, u32 thiU, int tid) {
  u64 bits = 0;
#pragma unroll
  for (int k2 = 0; k2 < 16; k2++) {
    int k = (k2 + (tid >> 1)) & 15;
    u32 v4 = cImgW[tid * 16 + k];
    u32 m = 0;
    if ((v4 & 0xFFu) > thiU)         m |= 1u;
    if (((v4 >> 8) & 0xFFu) > thiU)  m |= 2u;
    if (((v4 >> 16) & 0xFFu) > thiU) m |= 4u;
    if ((v4 >> 24) > thiU)           m |= 8u;
    bits |= (u64)m << (4 * k);
  }
  rows[tid] = bits;
}

__device__ __forceinline__ void erode_h(const u64* rows, u64* hrows, int r) {
  u64 wv[4], h0[4];
  for (int j = 0; j < 4; j++) { wv[j] = rows[r * 4 + j]; h0[j] = wv[j]; }
  for (int s = 1; s <= 5; s++)
    for (int j = 0; j < 4; j++) {
      u64 hi = (j < 3) ? wv[j + 1] : ~0ull;
      u64 lo = (j > 0) ? wv[j - 1] : ~0ull;
      h0[j] &= ((wv[j] >> s) | (hi << (64 - s))) & ((wv[j] << s) | (lo >> (64 - s)));
    }
  for (int j = 0; j < 4; j++) hrows[r * 4 + j] = h0[j];
}

__device__ __forceinline__ void erode_v(const u64* hrows, u64* rows, int r) {
  u64 res[4] = {hrows[r * 4], hrows[r * 4 + 1], hrows[r * 4 + 2], hrows[r * 4 + 3]};
  for (int dr = -5; dr <= 5; dr++) {
    if (dr == 0) continue;
    int rr = r + dr;
    if (rr < 0 || rr >= 256) continue;
    for (int j = 0; j < 4; j++) res[j] &= hrows[rr * 4 + j];
  }
  for (int j = 0; j < 4; j++) rows[r * 4 + j] = res[j];
}

// ---- generic top-100 seeding from an idx list (cold fg path).
__device__ void seed_generic(u64* lst2, u32 n, u32 k0, u32 k1, u32 bimg, u64* seedRows,
                             u32* hist, u32* eqA, u32* scal, u32* ws, bool dead, int tid) {
  u32* sc = scal + 2;
  seedRows[tid] = 0;
  for (u32 e = tid; e < n; e += 1024) {
    u32 idx = (u32)(lst2[e] & 0xFFFFu);
    u32 m = score_bits(k0, k1, (bimg << 16) | idx) >> 9;
    lst2[e] = ((u64)m << 16) | idx;
    atomicAdd(&hist[m >> 12], 1u);
  }
  if (tid == 0) scal[1] = 0;
  __syncthreads();
  u32 keff = n < TOPK ? n : TOPK;
  psel_full<2, 1024>(hist, keff, true, ws, sc, 4096, tid);
  u32 s0 = sc[0], Kr = sc[1];
  for (u32 e = tid; e < n; e += 1024) { u32 m = (u32)(lst2[e] >> 16); if ((m >> 12) == s0) atomicAdd(&hist[m & 0xFFFu], 1u); }
  __syncthreads();
  psel_full<4, 1024>(hist, Kr, true, ws, sc, 4096, tid);
  u32 S = (s0 << 12) | sc[0]; u32 tiesS = sc[1];
  for (u32 e = tid; e < n; e += 1024) {
    u64 le = lst2[e]; u32 m = (u32)(le >> 16); u32 idx = (u32)(le & 0xFFFFu);
    if (m > S) { if (!dead) atomicOr(&seedRows[idx >> 6], 1ull << (idx & 63)); }
    else if (m == S) { u32 p = atomicAdd(&scal[1], 1u); if (p < 256) eqA[p] = idx; }
  }
  __syncthreads();
  if (tid == 0) {
    u32 ne = scal[1] < 256u ? scal[1] : 256u;
    for (u32 i2 = 1; i2 < ne; i2++) { u32 v = eqA[i2]; int j = (int)i2 - 1; while (j >= 0 && eqA[j] > v) { eqA[j + 1] = eqA[j]; j--; } eqA[j + 1] = v; }
    scal[4] = ne;
  }
  __syncthreads();
  { u32 ne = scal[4]; u32 tk = tiesS < ne ? tiesS : ne;
    if (!dead && (u32)tid < tk) { u32 idx = eqA[tid]; atomicOr(&seedRows[idx >> 6], 1ull << (idx & 63)); } }
  __syncthreads();
}

__global__ __launch_bounds__(1024, 4) void k_all(const float* __restrict__ x,
                                                 u32 kf0, u32 kf1, u32 kb0, u32 kb1,
                                                 int* __restrict__ out) {
  __shared__ __align__(16) char arena[ARENA_BYTES];
  const int b = blockIdx.x, tid = threadIdx.x;
  const int lane = tid & 63;

  u64* lst    = (u64*)(arena + OFF_LST);
  u32* cImgW  = (u32*)(arena + OFF_CIMG);
  u32* hO4    = (u32*)(arena + OFF_HO4);
  u32* hist   = (u32*)(arena + OFF_HIST);
  u32* eqA    = (u32*)(arena + OFF_EQ);
  u32* scal   = (u32*)(arena + OFF_SCAL);
  u32* ws     = scal + 10;
  u32* sc     = scal + 2;
  u64* rows   = (u64*)(arena + OFF_ROWS);
  u64* hrows  = (u64*)(arena + OFF_HROWS);
  u64* fgList = (u64*)(arena + OFF_FGL);
  u64* seedB  = (u64*)(arena + OFF_SEEDB);
  u64* seedF  = (u64*)(arena + OFF_SEEDF);

  const u32 BND = __float_as_uint(0.110f);
  const float4* img4 = (const float4*)(x + (size_t)b * HWN);
  const float* img = x + (size_t)b * HWN;
  int4v* out4 = (int4v*)(out + (size_t)b * HWN);

  // ---- I0: zero
  hO4[tid] = 0;
  if (tid < 32) hO4[1024 + tid] = 0;
  hist[tid] = 0; hist[tid + 1024] = 0;
  if (tid < 10) scal[tid] = 0;
  __syncthreads();

  // ---- I1: single scan: cImg pack, otsu hist (4-way privatized),
  //      cam-stage1 count, scan-based push
  u32* myHO = hO4 + (tid >> 8) * 264;     // per-4-wave-group copy, bank-staggered
#pragma unroll
  for (int half = 0; half < 2; ++half) {
    float4 v[8];
#pragma unroll
    for (int k = 0; k < 8; k++) v[k] = img4[((half * 8 + k) << 10) + tid];
    u32 nq = 0;
#pragma unroll
    for (int k = 0; k < 8; k++) {
      u32 c0 = (u32)(int)(v[k].x * 255.0f);
      u32 c1 = (u32)(int)(v[k].y * 255.0f);
      u32 c2 = (u32)(int)(v[k].z * 255.0f);
      u32 c3 = (u32)(int)(v[k].w * 255.0f);
      atomicAdd(&myHO[c0], 1u); atomicAdd(&myHO[c1], 1u);
      atomicAdd(&myHO[c2], 1u); atomicAdd(&myHO[c3], 1u);
      cImgW[((half * 8 + k) << 10) + tid] = c0 | (c1 << 8) | (c2 << 16) | (c3 << 24);
      u32 q0 = __float_as_uint(v[k].x), q1 = __float_as_uint(v[k].y);
      u32 q2 = __float_as_uint(v[k].z), q3 = __float_as_uint(v[k].w);
      if (q0 < BND) { nq++; atomicAdd(&hist[q0 >> 19], 1u); }
      if (q1 < BND) { nq++; atomicAdd(&hist[q1 >> 19], 1u); }
      if (q2 < BND) { nq++; atomicAdd(&hist[q2 >> 19], 1u); }
      if (q3 < BND) { nq++; atomicAdd(&hist[q3 >> 19], 1u); }
    }
    u32 incl = wscan_incl(nq, lane);
    u32 wtot = __shfl(incl, 63, 64);
    u32 base = 0;
    if (lane == 0) base = atomicAdd(&scal[0], wtot);
    base = __shfl(base, 0, 64);
    u32 pos = base + incl - nq;
#pragma unroll
    for (int k = 0; k < 8; k++) {
      u32 q0 = __float_as_uint(v[k].x), q1 = __float_as_uint(v[k].y);
      u32 q2 = __float_as_uint(v[k].z), q3 = __float_as_uint(v[k].w);
      u32 pix = (u32)((((half * 8 + k) << 10) + tid) * 4);
      if (q0 < BND) { if (pos < CAP) lst[pos] = ((u64)q0 << 16) | pix; pos++; }
      if (q1 < BND) { if (pos < CAP) lst[pos] = ((u64)q1 << 16) | (pix + 1); pos++; }
      if (q2 < BND) { if (pos < CAP) lst[pos] = ((u64)q2 << 16) | (pix + 2); pos++; }
      if (q3 < BND) { if (pos < CAP) lst[pos] = ((u64)q3 << 16) | (pix + 3); pos++; }
    }
  }
  __syncthreads();
  u32 cntBelow = scal[0];
  bool fastOK = (cntBelow >= K_BG && cntBelow <= CAP);

  // ---- I2a: Otsu (wave 0) ∥ cam psel stage1 scan (tid>=512)
  {
    u32 h1v[4], loc1 = 0, inc1 = 0;
    if (tid < 64) otsu_wave0(hO4, scal, lane);
    if (tid >= 512) pselA<4, 512>(hist, ws, tid - 512, h1v, loc1, inc1);
    __syncthreads();
    // ---- I2b: psel stage1 finish ∥ zero hist[0..2047] (tid<512)
    if (tid >= 512) pselB<4, 512>(K_BG, false, ws, sc, tid - 512, h1v, loc1, inc1);
    else { hist[tid*4] = 0; hist[tid*4+1] = 0; hist[tid*4+2] = 0; hist[tid*4+3] = 0; }
    __syncthreads();
  }
  u32 thiU = scal[8];
  bool dead = scal[5] != 0u;

  u32 listN;
  if (fastOK) {
    listN = cntBelow;
    u32 cb0 = sc[0], Kb = sc[1];
    // ---- I4: stage2 count ∥ ROI bits
    for (u32 e = tid; e < listN; e += 1024) { u32 q = (u32)(lst[e] >> 16); if ((q >> 19) == cb0) atomicAdd(&hist[(q >> 8) & 0x7FFu], 1u); }
    roi_bits(cImgW, rows, thiU, tid);
    __syncthreads();
    // ---- I5a: psel stage2 scan (tid<512) ∥ erosion-h (512..767)
    u32 h2v[4], loc2 = 0, inc2 = 0;
    if (tid < 512) pselA<4, 512>(hist, ws, tid, h2v, loc2, inc2);
    else if (tid < 768) erode_h(rows, hrows, tid - 512);
    __syncthreads();
    // ---- I5b: psel stage2 finish ∥ erosion-v (512..767)
    if (tid < 512) pselB<4, 512>(Kb, false, ws, sc, tid, h2v, loc2, inc2);
    else if (tid < 768) erode_v(hrows, rows, tid - 512);
    __syncthreads();
    u32 cb1 = sc[0], Kc = sc[1];
    u32 hi22 = (cb0 << 11) | cb1;
    // ---- I6: collect stage3-bin entries ∥ fg extract ∥ zero hist[0..4095]
    for (u32 e = tid; e < listN; e += 1024) {
      u64 le = lst[e]; u32 q = (u32)(le >> 16);
      if ((q >> 8) == hi22) { u32 p = atomicAdd(&scal[1], 1u); if (p < 256) eqA[p] = ((q & 0xFFu) << 16) | (u32)(le & 0xFFFFu); }
    }
    { u64 wv = rows[tid];
      while (wv) { int bit = __ffsll((long long)wv) - 1; wv &= wv - 1; u32 p = atomicAdd(&scal[7], 1u); if (p < FG_CAP) fgList[p] = (u64)(u32)(tid * 64 + bit); } }
    hist[tid] = 0; hist[tid + 1024] = 0; hist[tid + 2048] = 0; hist[tid + 3072] = 0;
    __syncthreads();
    // ---- I7: exact finish — sort bin entries asc by (low8, idx); rank-Kc element
    if (tid == 0) {
      u32 ne = scal[1] < 256u ? scal[1] : 256u;
      for (u32 i2 = 1; i2 < ne; i2++) { u32 v = eqA[i2]; int j = (int)i2 - 1; while (j >= 0 && eqA[j] > v) { eqA[j + 1] = eqA[j]; j--; } eqA[j + 1] = v; }
      u32 ent = eqA[Kc - 1];
      scal[26] = (hi22 << 8) | (ent >> 16);   // T (full float bits)
      scal[27] = ent & 0xFFFFu;               // tie-max idx at T
    }
    __syncthreads();
  } else {
    // ======== cold exact fallback: full-range recount from global ========
    for (int k2 = tid; k2 < 4096; k2 += 1024) hist[k2] = 0;
    __syncthreads();
    for (int c = 0; c < 64; c++) atomicAdd(&hist[__float_as_uint(img[(c << 10) + tid]) >> 19], 1u);
    __syncthreads();
    psel_full<2, 1024>(hist, K_BG, false, ws, sc, 2048, tid);
    u32 cb0 = sc[0], Kb = sc[1];
    if (tid == 0) scal[0] = 0;
    __syncthreads();
    for (int c = 0; c < 64; c++) {
      int i = (c << 10) + tid; u32 q = __float_as_uint(img[i]);
      if ((q >> 19) == cb0) { u32 p = atomicAdd(&scal[0], 1u); if (p < CAP) lst[p] = ((u64)q << 16) | (u32)i; }
    }
    __syncthreads();
    u32 ln = scal[0] < CAP ? scal[0] : CAP;
    for (u32 e = tid; e < ln; e += 1024) { u32 q = (u32)(lst[e] >> 16); atomicAdd(&hist[(q >> 8) & 0x7FFu], 1u); }
    __syncthreads();
    psel_full<2, 1024>(hist, Kb, false, ws, sc, 256, tid);
    u32 cb1 = sc[0], Kc = sc[1];
    u32 hi22 = (cb0 << 11) | cb1;
    for (u32 e = tid; e < ln; e += 1024) { u32 q = (u32)(lst[e] >> 16); if ((q >> 8) == hi22) atomicAdd(&hist[q & 0xFFu], 1u); }
    __syncthreads();
    psel_full<1, 256>(hist, Kc, false, ws, sc, 2048, tid);
    u32 T0 = (hi22 << 8) | sc[0];
    u32 tiesCam = sc[1];
    if (tid == 0) scal[1] = 0;
    __syncthreads();
    for (u32 e = tid; e < ln; e += 1024) {
      u64 le = lst[e];
      if ((u32)(le >> 16) == T0) { u32 p = atomicAdd(&scal[1], 1u); if (p < 256) eqA[p] = (u32)(le & 0xFFFFu); }
    }
    __syncthreads();
    if (tid == 0) {
      u32 ne = scal[1] < 256u ? scal[1] : 256u;
      for (u32 i2 = 1; i2 < ne; i2++) { u32 v = eqA[i2]; int j = (int)i2 - 1; while (j >= 0 && eqA[j] > v) { eqA[j + 1] = eqA[j]; j--; } eqA[j + 1] = v; }
      u32 tmF = (tiesCam > 0 && tiesCam <= ne) ? eqA[tiesCam - 1] : ((tiesCam > 0) ? 0xFFFFFFFEu : 0xFFFFFFFFu);
      scal[9] = tmF;
      scal[26] = T0;
      scal[27] = tmF;
      scal[0] = 0;
    }
    __syncthreads();
    u32 tmaxF = scal[9];
    for (int c = 0; c < 64; c++) {
      int i = (c << 10) + tid; u32 q = __float_as_uint(img[i]);
      bool sel = (q < T0) || (q == T0 && tmaxF != 0xFFFFFFFFu && (u32)i <= tmaxF);
      if (sel) { u32 p = atomicAdd(&scal[0], 1u); if (p < CAP) lst[p] = ((u64)q << 16) | (u32)i; }
    }
    roi_bits(cImgW, rows, thiU, tid);
    __syncthreads();
    if (tid < 256) erode_h(rows, hrows, tid);
    __syncthreads();
    if (tid < 256) erode_v(hrows, rows, tid);
    __syncthreads();
    { u64 wv = rows[tid];
      while (wv) { int bit = __ffsll((long long)wv) - 1; wv &= wv - 1; u32 p = atomicAdd(&scal[7], 1u); if (p < FG_CAP) fgList[p] = (u64)(u32)(tid * 64 + bit); } }
    hist[tid + 2048] = 0; hist[tid + 3072] = 0;
    __syncthreads();
    listN = scal[0] < CAP ? scal[0] : CAP;
  }

  u32 T = scal[26];
  u32 camTmax = scal[27];
  u32 fgN = scal[7] < FG_CAP ? scal[7] : FG_CAP;
  if (fgN > 0) seed_generic(fgList, fgN, kf0, kf1, (u32)b, seedF, hist, eqA, scal, ws, dead, tid);

  // ---- I8a: read+filter candidates into registers
  u64 mine[8]; int nm = 0;
  for (u32 e = tid; e < listN; e += 1024) {
    u64 le = lst[e]; u32 q = (u32)(le >> 16); u32 idx = (u32)(le & 0xFFFFu);
    if (q < T || (q == T && idx <= camTmax)) { if (nm < 8) mine[nm++] = le; }
  }
  if (tid == 0) { scal[1] = 0; scal[6] = 0; }
  __syncthreads();
  // ---- I8b: compact + threefry score + bg stage1 count (4096 bins); init seeds
  {
    u32 nmU = (u32)nm;
    u32 incl = wscan_incl(nmU, lane);
    u32 wtot = __shfl(incl, 63, 64);
    u32 base2 = 0;
    if (lane == 0) base2 = atomicAdd(&scal[6], wtot);
    base2 = __shfl(base2, 0, 64);
    u32 my = base2 + incl - nmU;
    for (int k2 = 0; k2 < nm; k2++) {
      u32 idx = (u32)(mine[k2] & 0xFFFFu);
      u32 m = score_bits(kb0, kb1, ((u32)b << 16) | idx) >> 9;
      if (my + (u32)k2 < CAP) lst[my + k2] = ((u64)m << 16) | idx;
      atomicAdd(&hist[m >> 11], 1u);
    }
    seedB[tid] = 0;
    if (fgN == 0) seedF[tid] = 0;
  }
  __syncthreads();
  u32 candN = scal[6] < CAP ? scal[6] : CAP;
  u32 keff = candN < TOPK ? candN : TOPK;

  if (keff > 0) {
    // ---- I9: bg psel over 4096 bins (desc)
    u32 hb1[4], locb1 = 0, incb1 = 0;
    pselA<4, 1024>(hist, ws, tid, hb1, locb1, incb1);
    __syncthreads();
    pselB<4, 1024>(keff, true, ws, sc, tid, hb1, locb1, incb1);
    __syncthreads();
    u32 binB = sc[0], Krb = sc[1];
    // ---- I10: collect bin entries packed (invLow11<<16)|idx  (asc == m desc, idx asc)
    for (u32 e = tid; e < candN; e += 1024) {
      u64 le = lst[e]; u32 m = (u32)(le >> 16);
      if ((m >> 11) == binB) {
        u32 k2 = ((0x7FFu - (m & 0x7FFu)) << 16) | (u32)(le & 0xFFFFu);
        u32 p = atomicAdd(&scal[1], 1u); if (p < 256) eqA[p] = k2;
      }
    }
    __syncthreads();
    // ---- I11: tiny sort; rank-Krb element
    if (tid == 0) {
      u32 ne = scal[1] < 256u ? scal[1] : 256u;
      for (u32 i2 = 1; i2 < ne; i2++) { u32 v = eqA[i2]; int j = (int)i2 - 1; while (j >= 0 && eqA[j] > v) { eqA[j + 1] = eqA[j]; j--; } eqA[j + 1] = v; }
      scal[26] = eqA[Krb - 1];
    }
    __syncthreads();
    u32 key2K = scal[26];
    // ---- I12: mark
    if (!dead) {
      for (u32 e = tid; e < candN; e += 1024) {
        u64 le = lst[e]; u32 m = (u32)(le >> 16); u32 idx = (u32)(le & 0xFFFFu);
        u32 hb = m >> 11;
        u32 k2 = ((0x7FFu - (m & 0x7FFu)) << 16) | idx;
        bool sel = (hb > binB) || (hb == binB && k2 <= key2K);
        if (sel) atomicOr(&seedB[idx >> 6], 1ull << (idx & 63));
      }
    }
    __syncthreads();
  }

  // ---- dilation + conflict resolve + nt int4 emit
  u64* fvL = (u64*)(arena + OFF_FVL);
  u64* bvL = (u64*)(arena + OFF_BVL);
  u64* fhL = (u64*)(arena + OFF_FHL);
  u64* bhL = (u64*)(arena + OFF_BHL);
  {
    int r = tid >> 2;
    u64 vf = seedF[tid], vb = seedB[tid];
    if (r > 0)   { vf |= seedF[tid - 4]; vb |= seedB[tid - 4]; }
    if (r < 255) { vf |= seedF[tid + 4]; vb |= seedB[tid + 4]; }
    fvL[tid] = vf; bvL[tid] = vb;
  }
  __syncthreads();
  {
    int j = tid & 3;
    u64 v = fvL[tid];
    u64 L = (j > 0) ? fvL[tid - 1] : 0ull;
    u64 R = (j < 3) ? fvL[tid + 1] : 0ull;
    fhL[tid] = v | (v << 1) | (L >> 63) | (v >> 1) | (R << 63);
    v = bvL[tid];
    L = (j > 0) ? bvL[tid - 1] : 0ull;
    R = (j < 3) ? bvL[tid + 1] : 0ull;
    bhL[tid] = v | (v << 1) | (L >> 63) | (v >> 1) | (R << 63);
  }
  __syncthreads();
  for (int it = 0; it < 16; it++) {
    int idx4 = it * 1024 + tid;
    int word = idx4 >> 4;
    int sh = (idx4 & 15) * 4;
    u32 fb = (u32)(fhL[word] >> sh) & 0xFu;
    u32 gb = (u32)(bhL[word] >> sh) & 0xFu;
    u32 e = fb ^ gb;
    int4v o;
    o.x = (e & 1u)        ? (int)(fb & 1u)        : -255;
    o.y = ((e >> 1) & 1u) ? (int)((fb >> 1) & 1u) : -255;
    o.z = ((e >> 2) & 1u) ? (int)((fb >> 2) & 1u) : -255;
    o.w = ((e >> 3) & 1u) ? (int)((fb >> 3) & 1u) : -255;
    __builtin_nontemporal_store(o, out4 + idx4);
  }
}

extern "C" void kernel_launch(void* const* d_in, const int* in_sizes, int n_in,
                              void* d_out, int out_size, void* d_ws, size_t ws_size,
                              hipStream_t stream) {
  const float* x = (const float*)d_in[0];
  int* out = (int*)d_out;

  u32 kf0, kf1, kb0, kb1;
#if PARTITIONABLE
  threefry2x32(0u, 42u, 0u, 0u, kf0, kf1);
  threefry2x32(0u, 42u, 0u, 1u, kb0, kb1);
#else
  u32 a0, a1, c0, c1;
  threefry2x32(0u, 42u, 0u, 2u, a0, a1);
  threefry2x32(0u, 42u, 1u, 3u, c0, c1);
  kf0 = a0; kf1 = c0; kb0 = a1; kb1 = c1;
#endif

  k_all<<<BB, 1024, 0, stream>>>(x, kf0, kf1, kb0, kb1, out);
}